// Round 8
// baseline (292.716 us; speedup 1.0000x reference)
//
#include <hip/hip_runtime.h>
#include <cstdint>
#include <cstddef>

// Problem constants (fixed by the reference)
#define T_TOK 8192
#define DIM   1024   // D
#define FF    512    // F
#define NE    8      // experts
#define NSLOT 16384  // T*K
#define BM    128    // M-tile rows (both fast GEMMs)
#define MAXBLK (NSLOT / BM + NE)   // 136 = 8*17: worst-case Σ ceil(n_e/BM)
#define NGRID  (8 * MAXBLK)        // 1088 grid slots for the GEMMs

typedef short s16x8 __attribute__((ext_vector_type(8)));   // 8 bf16 (4 VGPRs) - MFMA A/B frag
typedef float f32x4 __attribute__((ext_vector_type(4)));   // MFMA C/D frag

// f32 -> bf16 (round-to-nearest-even), returns bits in low 16
__device__ __forceinline__ unsigned int f2bf(float f) {
    union { float f; unsigned int u; } v; v.f = f;
    return (v.u + 0x7FFFu + ((v.u >> 16) & 1u)) >> 16;
}
__device__ __forceinline__ float bf2f(unsigned short b) {
    union { unsigned int u; float f; } v; v.u = ((unsigned int)b) << 16;
    return v.f;
}
__device__ __forceinline__ int pack2(float a, float b) {
    return (int)f2bf(a) | ((int)f2bf(b) << 16);
}
__device__ __forceinline__ int4 cvt8(const float* p) {
    float4 x = *(const float4*)p;
    float4 y = *(const float4*)(p + 4);
    int4 r;
    r.x = pack2(x.x, x.y); r.y = pack2(x.z, x.w);
    r.z = pack2(y.x, y.y); r.w = pack2(y.z, y.w);
    return r;
}

// async global(per-lane addr) -> LDS(wave-uniform base + lane*16)
__device__ __forceinline__ void gload16(const unsigned short* g, unsigned short* l) {
    __builtin_amdgcn_global_load_lds(
        (const __attribute__((address_space(1))) void*)g,
        (__attribute__((address_space(3))) void*)l, 16, 0, 0);
}

// ---------------- routing (split 3-kernel form: replay-stable in rounds 1-6) ----------------
__global__ void route_count(const int* __restrict__ idx, int* counts) {
    int s = blockIdx.x * 256 + threadIdx.x;
    if (s < NSLOT) atomicAdd(&counts[idx[s]], 1);
}

// 1 thread: offsets + alive-y tables + balanced XCD grid map.
// Grid map: slot g -> xcd = g&7 (linear dispatch round-robins XCDs),
// bx = (g>>3)&7 (8 blocks sharing one A-tile are adjacent on one XCD),
// y_local = g>>6.  Alive y-tiles split into 8 near-equal expert-contiguous
// chunks so no XCD is overloaded (round-6 lesson: pads all on XCD7 cost ~6%).
__global__ void route_scan(const int* __restrict__ counts, int* offsets, int* cursor,
                           int* blk_e, int* blk_by, int* blk_y) {
    if (threadIdx.x == 0) {
        int acc = 0, nb = 0;
        for (int e = 0; e < NE; ++e) {
            offsets[e] = acc; cursor[e] = acc;
            const int nby = (counts[e] + BM - 1) / BM;
            for (int b = 0; b < nby; ++b) { blk_e[nb] = e; blk_by[nb] = b; ++nb; }
            acc += counts[e];
        }
        offsets[NE] = acc;
        for (int b = nb; b < MAXBLK; ++b) { blk_e[b] = -1; blk_by[b] = 0; }
        // balanced per-XCD chunks of the alive-y list
        const int q = nb / 8, r = nb % 8;
        for (int g = 0; g < NGRID; ++g) {
            const int x  = g & 7;
            const int yl = g >> 6;
            const int cx = q + (x < r ? 1 : 0);
            const int sx = x * q + (x < r ? x : r);
            blk_y[g] = (yl < cx) ? (sx + yl) : -1;
        }
    }
}
__global__ void route_scatter(const int* __restrict__ idx, int* cursor,
                              int* row_slot, int* slot_pos) {
    int s = blockIdx.x * 256 + threadIdx.x;
    if (s < NSLOT) {
        int e = idx[s];
        int p = atomicAdd(&cursor[e], 1);
        row_slot[p] = s;
        slot_pos[s] = p;     // inverse map: slot -> compact row
    }
}

// ---------------- one-time f32 -> bf16 conversion (hidden + both weights) ----------------
__global__ void cvt_all(const float* __restrict__ h, const float* __restrict__ g,
                        const float* __restrict__ d,
                        unsigned short* __restrict__ hb, unsigned short* __restrict__ gb,
                        unsigned short* __restrict__ db) {
    const int N1 = T_TOK * DIM / 8;          // 1,048,576
    const int N2 = NE * 2 * FF * DIM / 8;    // 1,048,576
    const int N3 = NE * DIM * FF / 8;        //   524,288
    const int stride = gridDim.x * 256;
    for (int i = blockIdx.x * 256 + threadIdx.x; i < N1 + N2 + N3; i += stride) {
        const float* s; unsigned short* o; int j;
        if (i < N1)            { s = h; o = hb; j = i; }
        else if (i < N1 + N2)  { s = g; o = gb; j = i - N1; }
        else                   { s = d; o = db; j = i - N1 - N2; }
        *(int4*)(o + (size_t)j * 8) = cvt8(s + (size_t)j * 8);
    }
}

// ================= fast path: 2-phase dbuf (static buffers), global_load_lds =================

#define G1_STAGE(BA, BB, T) do {                                                        \
    const int kn_ = (T) * 64;                                                           \
    _Pragma("unroll") for (int i_ = 0; i_ < 4; ++i_)                                    \
        gload16(hb + aoff[i_] + kn_, (BA) + (wv * 64 + i_ * 256) * 8);                  \
    _Pragma("unroll") for (int i_ = 0; i_ < 4; ++i_)                                    \
        gload16(gupb + boff[i_] + kn_, (BB) + (wv * 64 + i_ * 256) * 8);                \
} while (0)

#define G1_COMPUTE(BA, BB) do {                                                         \
    const char* Abc_ = (const char*)(BA);                                               \
    const char* Bbc_ = (const char*)(BB);                                               \
    _Pragma("unroll") for (int kk = 0; kk < 2; ++kk) {                                  \
        const int kc = kk * 4 + (lane >> 4);                                            \
        s16x8 af[4], bg[2], bu[2];                                                      \
        _Pragma("unroll") for (int m = 0; m < 4; ++m) {                                 \
            const int r = wr * 64 + m * 16 + (lane & 15);                               \
            af[m] = *(const s16x8*)(Abc_ + r * 128 + ((kc ^ (r & 7)) << 4)); }          \
        _Pragma("unroll") for (int n = 0; n < 2; ++n) {                                 \
            const int rg = wc * 32 + n * 16 + (lane & 15);                              \
            bg[n] = *(const s16x8*)(Bbc_ + rg * 128 + ((kc ^ (rg & 7)) << 4));          \
            const int ru = rg + 64;                                                     \
            bu[n] = *(const s16x8*)(Bbc_ + ru * 128 + ((kc ^ (ru & 7)) << 4)); }        \
        _Pragma("unroll") for (int m = 0; m < 4; ++m)                                   \
        _Pragma("unroll") for (int n = 0; n < 2; ++n) {                                 \
            ag[m][n] = __builtin_amdgcn_mfma_f32_16x16x32_bf16(af[m], bg[n], ag[m][n], 0, 0, 0); \
            au[m][n] = __builtin_amdgcn_mfma_f32_16x16x32_bf16(af[m], bu[n], au[m][n], 0, 0, 0); } \
    }                                                                                   \
} while (0)

// GEMM1: act = silu(X Wg^T) * (X Wu^T).  tile 128 rows x 64 act-cols (g+u), BK=64, 16 K-steps.
// grid: 1D NGRID via balanced map; 256 thr = 4 waves (2M x 2N)
__global__ __launch_bounds__(256) void gemm1_bf16(
    const unsigned short* __restrict__ hb,    // [T, D] bf16
    const unsigned short* __restrict__ gupb,  // [E, 2F, D] bf16
    const int* __restrict__ row_slot,
    const int* __restrict__ offsets,
    const int* __restrict__ blk_e,
    const int* __restrict__ blk_by,
    const int* __restrict__ blk_y,
    unsigned short* __restrict__ act)         // [NSLOT, F] bf16
{
    const int yy = blk_y[blockIdx.x];
    if (yy < 0 || yy >= MAXBLK) return;
    const int e  = blk_e[yy];
    if (e < 0) return;
    const int bx = (blockIdx.x >> 3) & 7;
    const int lby     = blk_by[yy];
    const int rowbase = offsets[e] + lby * BM;
    const int rowlim  = offsets[e + 1] - 1;
    const int nrows   = min(BM, offsets[e + 1] - rowbase);

    __shared__ __align__(16) unsigned short Ab0[BM * 64], Ab1[BM * 64];   // 16 KB each
    __shared__ __align__(16) unsigned short Bb0[128 * 64], Bb1[128 * 64]; // 16 KB each

    const int tid  = threadIdx.x;
    const int lane = tid & 63;
    const int wv   = tid >> 6;
    const int wr   = wv >> 1, wc = wv & 1;

    int aoff[4];
#pragma unroll
    for (int i = 0; i < 4; ++i) {
        const int ch = tid + i * 256;          // 1024 chunks = 128 rows x 8 col-chunks
        const int r = ch >> 3, c = ch & 7;
        int grow = rowbase + r; if (grow > rowlim) grow = rowlim;
        const int tok = row_slot[grow] >> 1;
        aoff[i] = tok * DIM + ((c ^ (r & 7)) << 3);
    }
    int boff[4];
#pragma unroll
    for (int i = 0; i < 4; ++i) {
        const int ch = tid + i * 256;
        const int r = ch >> 3, c = ch & 7;
        const int gr = (r < 64) ? (bx * 64 + r) : (FF + bx * 64 + r - 64);
        boff[i] = e * (2 * FF * DIM) + gr * DIM + ((c ^ (r & 7)) << 3);
    }

    const f32x4 zf = {0.f, 0.f, 0.f, 0.f};
    f32x4 ag[4][2], au[4][2];
#pragma unroll
    for (int m = 0; m < 4; ++m)
#pragma unroll
        for (int n = 0; n < 2; ++n) { ag[m][n] = zf; au[m][n] = zf; }

    G1_STAGE(Ab0, Bb0, 0);
    __syncthreads();

#pragma unroll 1
    for (int t = 0; t < DIM / 64; t += 2) {
        G1_STAGE(Ab1, Bb1, t + 1);
        G1_COMPUTE(Ab0, Bb0);
        __syncthreads();
        if (t + 2 < DIM / 64) G1_STAGE(Ab0, Bb0, t + 2);
        G1_COMPUTE(Ab1, Bb1);
        __syncthreads();
    }

    // epilogue: act = silu(g)*u -> bf16
#pragma unroll
    for (int m = 0; m < 4; ++m)
#pragma unroll
        for (int n = 0; n < 2; ++n) {
            const int col = bx * 64 + wc * 32 + n * 16 + (lane & 15);
#pragma unroll
            for (int i = 0; i < 4; ++i) {
                const int rl = wr * 64 + m * 16 + ((lane >> 4) << 2) + i;
                if (rl < nrows) {
                    const float g = ag[m][n][i];
                    const float u = au[m][n][i];
                    const float a = (g / (1.f + __expf(-g))) * u;
                    act[(size_t)(rowbase + rl) * FF + col] = (unsigned short)f2bf(a);
                }
            }
        }
}

#define G2_STAGE(BA, BB, T) do {                                                        \
    const int kn_ = (T) * 64;                                                           \
    _Pragma("unroll") for (int i_ = 0; i_ < 4; ++i_)                                    \
        gload16(act + aoff[i_] + kn_, (BA) + (wv * 64 + i_ * 256) * 8);                 \
    _Pragma("unroll") for (int i_ = 0; i_ < 4; ++i_)                                    \
        gload16(downb + boff[i_] + kn_, (BB) + (wv * 64 + i_ * 256) * 8);               \
} while (0)

#define G2_COMPUTE(BA, BB) do {                                                         \
    const char* Abc_ = (const char*)(BA);                                               \
    const char* Bbc_ = (const char*)(BB);                                               \
    _Pragma("unroll") for (int kk = 0; kk < 2; ++kk) {                                  \
        const int kc = kk * 4 + (lane >> 4);                                            \
        s16x8 af[4], bf[4];                                                             \
        _Pragma("unroll") for (int m = 0; m < 4; ++m) {                                 \
            const int r = wr * 64 + m * 16 + (lane & 15);                               \
            af[m] = *(const s16x8*)(Abc_ + r * 128 + ((kc ^ (r & 7)) << 4)); }          \
        _Pragma("unroll") for (int n = 0; n < 4; ++n) {                                 \
            const int r = wc * 64 + n * 16 + (lane & 15);                               \
            bf[n] = *(const s16x8*)(Bbc_ + r * 128 + ((kc ^ (r & 7)) << 4)); }          \
        _Pragma("unroll") for (int m = 0; m < 4; ++m)                                   \
        _Pragma("unroll") for (int n = 0; n < 4; ++n)                                   \
            acc[m][n] = __builtin_amdgcn_mfma_f32_16x16x32_bf16(af[m], bf[n], acc[m][n], 0, 0, 0); \
    }                                                                                   \
} while (0)

// GEMM2: per-slot result = act_row @ down^T (UNSCALED), stored dense to outslot.
// MODE 1: f32 outslot; MODE 2: bf16 outslot.  tile 128 x 128, BK=64, 8 K-steps.
// grid: 1D NGRID via balanced map; 256 thr = 4 waves (2M x 2N)
template <int MODE>
__global__ __launch_bounds__(256) void gemm2_slot(
    const unsigned short* __restrict__ act,   // [NSLOT, F] bf16
    const unsigned short* __restrict__ downb, // [E, D, F] bf16
    const int* __restrict__ row_slot,
    const int* __restrict__ offsets,
    const int* __restrict__ blk_e,
    const int* __restrict__ blk_by,
    const int* __restrict__ blk_y,
    void* __restrict__ outslot)               // [NSLOT, D] f32 or bf16
{
    const int yy = blk_y[blockIdx.x];
    if (yy < 0 || yy >= MAXBLK) return;
    const int e  = blk_e[yy];
    if (e < 0) return;
    const int bx = (blockIdx.x >> 3) & 7;
    const int lby     = blk_by[yy];
    const int rowbase = offsets[e] + lby * BM;
    const int nrows   = min(BM, offsets[e + 1] - rowbase);
    const int rowlim  = offsets[e + 1] - 1;

    __shared__ __align__(16) unsigned short Ab0[BM * 64], Ab1[BM * 64];
    __shared__ __align__(16) unsigned short Bb0[128 * 64], Bb1[128 * 64];

    const int tid  = threadIdx.x;
    const int lane = tid & 63;
    const int wv   = tid >> 6;
    const int wr   = wv >> 1, wc = wv & 1;

    int aoff[4];
#pragma unroll
    for (int i = 0; i < 4; ++i) {
        const int ch = tid + i * 256;
        const int r = ch >> 3, c = ch & 7;
        int grow = rowbase + r; if (grow > rowlim) grow = rowlim;
        aoff[i] = grow * FF + ((c ^ (r & 7)) << 3);
    }
    int boff[4];
#pragma unroll
    for (int i = 0; i < 4; ++i) {
        const int ch = tid + i * 256;
        const int r = ch >> 3, c = ch & 7;
        boff[i] = e * (DIM * FF) + (bx * 128 + r) * FF + ((c ^ (r & 7)) << 3);
    }

    const f32x4 zf = {0.f, 0.f, 0.f, 0.f};
    f32x4 acc[4][4];
#pragma unroll
    for (int m = 0; m < 4; ++m)
#pragma unroll
        for (int n = 0; n < 4; ++n) acc[m][n] = zf;

    G2_STAGE(Ab0, Bb0, 0);
    __syncthreads();

#pragma unroll 1
    for (int t = 0; t < FF / 64; t += 2) {
        G2_STAGE(Ab1, Bb1, t + 1);
        G2_COMPUTE(Ab0, Bb0);
        __syncthreads();
        if (t + 2 < FF / 64) G2_STAGE(Ab0, Bb0, t + 2);
        G2_COMPUTE(Ab1, Bb1);
        __syncthreads();
    }

    // epilogue: dense non-conflicting stores to this block's (row, col-range)
#pragma unroll
    for (int m = 0; m < 4; ++m)
#pragma unroll
        for (int i = 0; i < 4; ++i) {
            const int rl = wr * 64 + m * 16 + ((lane >> 4) << 2) + i;
            if (rl < nrows) {
                const size_t base = (size_t)(rowbase + rl) * DIM + bx * 128 + wc * 64 + (lane & 15);
                if (MODE == 1) {
                    float* o = (float*)outslot + base;
#pragma unroll
                    for (int n = 0; n < 4; ++n) o[n * 16] = acc[m][n][i];
                } else {
                    unsigned short* o = (unsigned short*)outslot + base;
#pragma unroll
                    for (int n = 0; n < 4; ++n) o[n * 16] = (unsigned short)f2bf(acc[m][n][i]);
                }
            }
        }
}

// combine: out[t] = w0 * outslot[pos(2t)] + w1 * outslot[pos(2t+1)]
template <int MODE>
__global__ __launch_bounds__(256) void combine_k(
    const void* __restrict__ outslot,
    const int* __restrict__ slot_pos,
    const float* __restrict__ tkw,
    float* __restrict__ out)
{
    const int i = blockIdx.x * 256 + threadIdx.x;   // [0, T*D/8)
    const int t = i >> 7;                            // DIM/8 = 128 chunks/token
    const int d = (i & 127) << 3;
    const int p0 = slot_pos[2 * t], p1 = slot_pos[2 * t + 1];
    const float w0 = tkw[2 * t],    w1 = tkw[2 * t + 1];
    float r0[8], r1[8];
    if (MODE == 1) {
        const float* s0 = (const float*)outslot + (size_t)p0 * DIM + d;
        const float* s1 = (const float*)outslot + (size_t)p1 * DIM + d;
        float4 a0 = *(const float4*)s0, a1 = *(const float4*)(s0 + 4);
        float4 b0 = *(const float4*)s1, b1 = *(const float4*)(s1 + 4);
        r0[0]=a0.x; r0[1]=a0.y; r0[2]=a0.z; r0[3]=a0.w; r0[4]=a1.x; r0[5]=a1.y; r0[6]=a1.z; r0[7]=a1.w;
        r1[0]=b0.x; r1[1]=b0.y; r1[2]=b0.z; r1[3]=b0.w; r1[4]=b1.x; r1[5]=b1.y; r1[6]=b1.z; r1[7]=b1.w;
    } else {
        const s16x8 a = *(const s16x8*)((const unsigned short*)outslot + (size_t)p0 * DIM + d);
        const s16x8 b = *(const s16x8*)((const unsigned short*)outslot + (size_t)p1 * DIM + d);
#pragma unroll
        for (int j = 0; j < 8; ++j) { r0[j] = bf2f((unsigned short)a[j]); r1[j] = bf2f((unsigned short)b[j]); }
    }
    float4 o0, o1;
    o0.x = w0*r0[0]+w1*r1[0]; o0.y = w0*r0[1]+w1*r1[1]; o0.z = w0*r0[2]+w1*r1[2]; o0.w = w0*r0[3]+w1*r1[3];
    o1.x = w0*r0[4]+w1*r1[4]; o1.y = w0*r0[5]+w1*r1[5]; o1.z = w0*r0[6]+w1*r1[6]; o1.w = w0*r0[7]+w1*r1[7];
    float* op = out + (size_t)t * DIM + d;
    *(float4*)op = o0;
    *(float4*)(op + 4) = o1;
}

// ================= fallback path (f32 in-kernel convert, atomic out) =================

__global__ __launch_bounds__(256) void moe_gemm1(
    const float* __restrict__ hidden, const float* __restrict__ gup,
    const int* __restrict__ row_slot, const int* __restrict__ offsets,
    unsigned short* __restrict__ act)
{
    const int e = blockIdx.z;
    const int row0 = offsets[e];
    const int n_e = offsets[e + 1] - row0;
    const int by = blockIdx.y;
    if (by * 128 >= n_e) return;
    const int bx = blockIdx.x;
    __shared__ __align__(16) unsigned short Abuf[128 * 64];
    __shared__ __align__(16) unsigned short Bbuf[128 * 64];
    char* Ab = (char*)Abuf; char* Bb = (char*)Bbuf;
    const int tid = threadIdx.x, lane = tid & 63, wv = tid >> 6;
    const int wr = wv >> 1, wc = wv & 1;
    const float* aptr[4]; const float* bptr[4]; int soff[4];
#pragma unroll
    for (int i = 0; i < 4; ++i) {
        const int chunk = tid + i * 256;
        const int r = chunk >> 3, c = chunk & 7;
        soff[i] = r * 128 + ((c ^ (r & 7)) << 4);
        int rr = by * 128 + r; if (rr >= n_e) rr = n_e - 1;
        const int slot = row_slot[row0 + rr];
        aptr[i] = hidden + (size_t)(slot >> 1) * DIM + c * 8;
        const int gr = (r < 64) ? (bx * 64 + r) : (FF + bx * 64 + (r - 64));
        bptr[i] = gup + (size_t)e * (2 * FF * DIM) + (size_t)gr * DIM + c * 8;
    }
    const f32x4 zf = {0.f, 0.f, 0.f, 0.f};
    f32x4 acc_g[4][2], acc_u[4][2];
#pragma unroll
    for (int m = 0; m < 4; ++m)
#pragma unroll
        for (int n = 0; n < 2; ++n) { acc_g[m][n] = zf; acc_u[m][n] = zf; }
    for (int k0 = 0; k0 < DIM; k0 += 64) {
        __syncthreads();
#pragma unroll
        for (int i = 0; i < 4; ++i) *(int4*)(Ab + soff[i]) = cvt8(aptr[i] + k0);
#pragma unroll
        for (int i = 0; i < 4; ++i) *(int4*)(Bb + soff[i]) = cvt8(bptr[i] + k0);
        __syncthreads();
#pragma unroll
        for (int kk = 0; kk < 2; ++kk) {
            const int kc = kk * 4 + (lane >> 4);
            s16x8 af[4], bg[2], bu[2];
#pragma unroll
            for (int m = 0; m < 4; ++m) {
                const int r = wr * 64 + m * 16 + (lane & 15);
                af[m] = *(const s16x8*)(Ab + r * 128 + ((kc ^ (r & 7)) << 4));
            }
#pragma unroll
            for (int n = 0; n < 2; ++n) {
                const int rg = wc * 32 + n * 16 + (lane & 15);
                bg[n] = *(const s16x8*)(Bb + rg * 128 + ((kc ^ (rg & 7)) << 4));
                const int ru = rg + 64;
                bu[n] = *(const s16x8*)(Bb + ru * 128 + ((kc ^ (ru & 7)) << 4));
            }
#pragma unroll
            for (int m = 0; m < 4; ++m)
#pragma unroll
                for (int n = 0; n < 2; ++n) {
                    acc_g[m][n] = __builtin_amdgcn_mfma_f32_16x16x32_bf16(af[m], bg[n], acc_g[m][n], 0, 0, 0);
                    acc_u[m][n] = __builtin_amdgcn_mfma_f32_16x16x32_bf16(af[m], bu[n], acc_u[m][n], 0, 0, 0);
                }
        }
    }
#pragma unroll
    for (int m = 0; m < 4; ++m)
#pragma unroll
        for (int n = 0; n < 2; ++n) {
            const int col = bx * 64 + wc * 32 + n * 16 + (lane & 15);
#pragma unroll
            for (int i = 0; i < 4; ++i) {
                const int rl = wr * 64 + m * 16 + ((lane >> 4) << 2) + i;
                const int rr = by * 128 + rl;
                if (rr < n_e) {
                    const float g = acc_g[m][n][i];
                    const float u = acc_u[m][n][i];
                    const float a = (g / (1.f + __expf(-g))) * u;
                    act[(size_t)(row0 + rr) * FF + col] = (unsigned short)f2bf(a);
                }
            }
        }
}

__global__ __launch_bounds__(256) void moe_gemm2(
    const unsigned short* __restrict__ act, const float* __restrict__ down,
    const int* __restrict__ row_slot, const int* __restrict__ offsets,
    const float* __restrict__ tkw, float* __restrict__ out)
{
    const int e = blockIdx.z;
    const int row0 = offsets[e];
    const int n_e = offsets[e + 1] - row0;
    const int by = blockIdx.y;
    if (by * 128 >= n_e) return;
    const int bx = blockIdx.x;
    __shared__ __align__(16) unsigned short Abuf[128 * 64];
    __shared__ __align__(16) unsigned short Bbuf[128 * 64];
    char* Ab = (char*)Abuf; char* Bb = (char*)Bbuf;
    const int tid = threadIdx.x, lane = tid & 63, wv = tid >> 6;
    const int wr = wv >> 1, wc = wv & 1;
    const unsigned short* aptr[4]; const float* bptr[4]; int soff[4];
#pragma unroll
    for (int i = 0; i < 4; ++i) {
        const int chunk = tid + i * 256;
        const int r = chunk >> 3, c = chunk & 7;
        soff[i] = r * 128 + ((c ^ (r & 7)) << 4);
        int rr = by * 128 + r; if (rr >= n_e) rr = n_e - 1;
        aptr[i] = act + (size_t)(row0 + rr) * FF + c * 8;
        bptr[i] = down + (size_t)e * (DIM * FF) + (size_t)(bx * 128 + r) * FF + c * 8;
    }
    const f32x4 zf = {0.f, 0.f, 0.f, 0.f};
    f32x4 acc[4][4];
#pragma unroll
    for (int m = 0; m < 4; ++m)
#pragma unroll
        for (int n = 0; n < 4; ++n) acc[m][n] = zf;
    for (int k0 = 0; k0 < FF; k0 += 64) {
        __syncthreads();
#pragma unroll
        for (int i = 0; i < 4; ++i) *(int4*)(Ab + soff[i]) = *(const int4*)(aptr[i] + k0);
#pragma unroll
        for (int i = 0; i < 4; ++i) *(int4*)(Bb + soff[i]) = cvt8(bptr[i] + k0);
        __syncthreads();
#pragma unroll
        for (int kk = 0; kk < 2; ++kk) {
            const int kc = kk * 4 + (lane >> 4);
            s16x8 af[4], bf[4];
#pragma unroll
            for (int m = 0; m < 4; ++m) {
                const int r = wr * 64 + m * 16 + (lane & 15);
                af[m] = *(const s16x8*)(Ab + r * 128 + ((kc ^ (r & 7)) << 4));
            }
#pragma unroll
            for (int n = 0; n < 4; ++n) {
                const int r = wc * 64 + n * 16 + (lane & 15);
                bf[n] = *(const s16x8*)(Bb + r * 128 + ((kc ^ (r & 7)) << 4));
            }
#pragma unroll
            for (int m = 0; m < 4; ++m)
#pragma unroll
                for (int n = 0; n < 4; ++n)
                    acc[m][n] = __builtin_amdgcn_mfma_f32_16x16x32_bf16(af[m], bf[n], acc[m][n], 0, 0, 0);
        }
    }
#pragma unroll
    for (int m = 0; m < 4; ++m)
#pragma unroll
        for (int i = 0; i < 4; ++i) {
            const int rl = wr * 64 + m * 16 + ((lane >> 4) << 2) + i;
            const int rr = by * 128 + rl;
            if (rr < n_e) {
                const int slot = row_slot[row0 + rr];
                const float w = tkw[slot];
                float* orow = out + (size_t)(slot >> 1) * DIM + bx * 128 + wc * 64 + (lane & 15);
#pragma unroll
                for (int n = 0; n < 4; ++n)
                    unsafeAtomicAdd(orow + n * 16, acc[m][n][i] * w);
            }
        }
}

extern "C" void kernel_launch(void* const* d_in, const int* in_sizes, int n_in,
                              void* d_out, int out_size, void* d_ws, size_t ws_size,
                              hipStream_t stream)
{
    const float* hidden = (const float*)d_in[0];
    const int*   idx    = (const int*)  d_in[1];
    const float* tkw    = (const float*)d_in[2];
    const float* gup    = (const float*)d_in[3];
    const float* down   = (const float*)d_in[4];
    float* out = (float*)d_out;

    // workspace layout
    const size_t ACT = (size_t)NSLOT * FF * 2;        // 16 MB
    const size_t HB  = (size_t)T_TOK * DIM * 2;       // 16 MB
    const size_t GB  = (size_t)NE * 2 * FF * DIM * 2; // 16 MB
    const size_t DB  = (size_t)NE * DIM * FF * 2;     //  8 MB
    const size_t RS  = (size_t)NSLOT * 4;             // 64 KB (row_slot)
    const size_t SP  = (size_t)NSLOT * 4;             // 64 KB (slot_pos)
    const size_t CTRL = 8192;                         // offsets + blk tables + grid map
    const size_t OS32 = (size_t)NSLOT * DIM * 4;      // 64 MB (f32 outslot)
    const size_t OS16 = (size_t)NSLOT * DIM * 2;      // 32 MB (bf16 outslot)
    char* ws = (char*)d_ws;
    unsigned short* act = (unsigned short*)ws;

    const size_t base_need = ACT + HB + GB + DB + RS + SP + CTRL;
    int mode;                       // 1: f32 slot, 2: bf16 slot, 0: legacy atomic
    if      (ws_size >= base_need + OS32) mode = 1;
    else if (ws_size >= base_need + OS16) mode = 2;
    else if (ws_size >= ACT + RS + SP + CTRL) mode = 0;
    else mode = -1;
    if (mode < 0) return;

    unsigned short *hb = nullptr, *gb = nullptr, *db = nullptr;
    int *row_slot, *ctrl; void* outslot = nullptr;
    if (mode == 1 || mode == 2) {
        hb = (unsigned short*)(ws + ACT);
        gb = (unsigned short*)(ws + ACT + HB);
        db = (unsigned short*)(ws + ACT + HB + GB);
        row_slot = (int*)(ws + ACT + HB + GB + DB);
        ctrl     = (int*)(ws + ACT + HB + GB + DB + RS + SP);
        outslot  = (void*)(ws + base_need);
    } else {
        row_slot = (int*)(ws + ACT);
        ctrl     = (int*)(ws + ACT + RS + SP);
    }
    int* slot_pos = row_slot + NSLOT;
    int* offsets = ctrl;                         // [NE+1] (16 slots reserved)
    int* blk_e   = ctrl + 16;                    // [MAXBLK]
    int* blk_by  = ctrl + 16 + MAXBLK;           // [MAXBLK]
    int* blk_y   = ctrl + 16 + 2 * MAXBLK;       // [NGRID]
    int* counts  = ctrl + 16 + 2 * MAXBLK + NGRID;   // [8]
    int* cursor  = counts + 8;                       // [8]

    hipMemsetAsync(counts, 0, 8 * sizeof(int), stream);
    if (mode == 0)
        hipMemsetAsync(out, 0, (size_t)T_TOK * DIM * sizeof(float), stream);

    route_count  <<<NSLOT / 256, 256, 0, stream>>>(idx, counts);
    route_scan   <<<1, 64, 0, stream>>>(counts, offsets, cursor, blk_e, blk_by, blk_y);
    route_scatter<<<NSLOT / 256, 256, 0, stream>>>(idx, cursor, row_slot, slot_pos);

    if (mode == 1 || mode == 2) {
        cvt_all<<<2048, 256, 0, stream>>>(hidden, gup, down, hb, gb, db);
        gemm1_bf16<<<NGRID, 256, 0, stream>>>(
            hb, gb, row_slot, offsets, blk_e, blk_by, blk_y, act);
        if (mode == 1) {
            gemm2_slot<1><<<NGRID, 256, 0, stream>>>(
                act, db, row_slot, offsets, blk_e, blk_by, blk_y, outslot);
            combine_k<1><<<T_TOK * DIM / 8 / 256, 256, 0, stream>>>(outslot, slot_pos, tkw, out);
        } else {
            gemm2_slot<2><<<NGRID, 256, 0, stream>>>(
                act, db, row_slot, offsets, blk_e, blk_by, blk_y, outslot);
            combine_k<2><<<T_TOK * DIM / 8 / 256, 256, 0, stream>>>(outslot, slot_pos, tkw, out);
        }
    } else {
        moe_gemm1<<<dim3(FF / 64, 128, NE), 256, 0, stream>>>(hidden, gup, row_slot, offsets, act);
        moe_gemm2<<<dim3(DIM / 128, 128, NE), 256, 0, stream>>>(act, down, row_slot, offsets, tkw, out);
    }
}

// Round 9
// 211.070 us; speedup vs baseline: 1.3868x; 1.3868x over previous
//
#include <hip/hip_runtime.h>
#include <cstdint>
#include <cstddef>

// Problem constants (fixed by the reference)
#define T_TOK 8192
#define DIM   1024   // D
#define FF    512    // F
#define NE    8      // experts
#define NSLOT 16384  // T*K
#define BM    128    // M-tile rows (both fast GEMMs)
#define MAXBLK (NSLOT / BM + NE)   // 136: worst-case Σ ceil(n_e/BM)

typedef short s16x8 __attribute__((ext_vector_type(8)));   // 8 bf16 (4 VGPRs) - MFMA A/B frag
typedef float f32x4 __attribute__((ext_vector_type(4)));   // MFMA C/D frag

// f32 -> bf16 (round-to-nearest-even), returns bits in low 16
__device__ __forceinline__ unsigned int f2bf(float f) {
    union { float f; unsigned int u; } v; v.f = f;
    return (v.u + 0x7FFFu + ((v.u >> 16) & 1u)) >> 16;
}
__device__ __forceinline__ float bf2f(unsigned short b) {
    union { unsigned int u; float f; } v; v.u = ((unsigned int)b) << 16;
    return v.f;
}
__device__ __forceinline__ int pack2(float a, float b) {
    return (int)f2bf(a) | ((int)f2bf(b) << 16);
}
__device__ __forceinline__ int4 cvt8(const float* p) {
    float4 x = *(const float4*)p;
    float4 y = *(const float4*)(p + 4);
    int4 r;
    r.x = pack2(x.x, x.y); r.y = pack2(x.z, x.w);
    r.z = pack2(y.x, y.y); r.w = pack2(y.z, y.w);
    return r;
}

// async global(per-lane addr) -> LDS(wave-uniform base + lane*16)
__device__ __forceinline__ void gload16(const unsigned short* g, unsigned short* l) {
    __builtin_amdgcn_global_load_lds(
        (const __attribute__((address_space(1))) void*)g,
        (__attribute__((address_space(3))) void*)l, 16, 0, 0);
}

// ---------------- routing (split kernels; no global memset needed) ----------------
// route_count: 64 blocks x 256 thr; per-block LDS counts -> partial[block*8+e]
__global__ __launch_bounds__(256) void route_count(const int* __restrict__ idx,
                                                   int* __restrict__ partial) {
    __shared__ int cnt[NE];
    const int tid = threadIdx.x;
    if (tid < NE) cnt[tid] = 0;
    __syncthreads();
    atomicAdd(&cnt[idx[blockIdx.x * 256 + tid]], 1);
    __syncthreads();
    if (tid < NE) partial[blockIdx.x * NE + tid] = cnt[tid];
}

// route_scan: 1 block, 64 thr: sum partials, build offsets/cursor + alive-y tables
__global__ void route_scan(const int* __restrict__ partial, int* offsets, int* cursor,
                           int* blk_e, int* blk_by) {
    __shared__ int counts_s[NE];
    const int tid = threadIdx.x;
    if (tid < NE) {
        int s = 0;
        for (int b = 0; b < 64; ++b) s += partial[b * NE + tid];
        counts_s[tid] = s;
    }
    __syncthreads();
    if (tid == 0) {
        int acc = 0, nb = 0;
        for (int e = 0; e < NE; ++e) {
            offsets[e] = acc; cursor[e] = acc;
            const int nby = (counts_s[e] + BM - 1) / BM;
            for (int b = 0; b < nby; ++b) { blk_e[nb] = e; blk_by[nb] = b; ++nb; }
            acc += counts_s[e];
        }
        offsets[NE] = acc;
        for (int b = nb; b < MAXBLK; ++b) { blk_e[b] = -1; blk_by[b] = 0; }
    }
}
__global__ void route_scatter(const int* __restrict__ idx, int* cursor,
                              int* row_slot, int* slot_pos) {
    int s = blockIdx.x * 256 + threadIdx.x;
    if (s < NSLOT) {
        int e = idx[s];
        int p = atomicAdd(&cursor[e], 1);
        row_slot[p] = s;
        slot_pos[s] = p;     // inverse map: slot -> compact row
    }
}

// ---------------- one-time f32 -> bf16 conversion (hidden + both weights) ----------------
__global__ void cvt_all(const float* __restrict__ h, const float* __restrict__ g,
                        const float* __restrict__ d,
                        unsigned short* __restrict__ hb, unsigned short* __restrict__ gb,
                        unsigned short* __restrict__ db) {
    const int N1 = T_TOK * DIM / 8;          // 1,048,576
    const int N2 = NE * 2 * FF * DIM / 8;    // 1,048,576
    const int N3 = NE * DIM * FF / 8;        //   524,288
    const int stride = gridDim.x * 256;
    for (int i = blockIdx.x * 256 + threadIdx.x; i < N1 + N2 + N3; i += stride) {
        const float* s; unsigned short* o; int j;
        if (i < N1)            { s = h; o = hb; j = i; }
        else if (i < N1 + N2)  { s = g; o = gb; j = i - N1; }
        else                   { s = d; o = db; j = i - N1 - N2; }
        *(int4*)(o + (size_t)j * 8) = cvt8(s + (size_t)j * 8);
    }
}

// ================= fast path: 2-phase dbuf (static buffers), global_load_lds =================
// grid: 2D (bx fastest, by) -- round-5 mapping, empirically fastest (69 vs 77 us);
// NOT XCD-swizzled: kernel is latency-bound, not HBM-bound, so parallel HBM streams win.

#define G1_STAGE(BA, BB, T) do {                                                        \
    const int kn_ = (T) * 64;                                                           \
    _Pragma("unroll") for (int i_ = 0; i_ < 4; ++i_)                                    \
        gload16(hb + aoff[i_] + kn_, (BA) + (wv * 64 + i_ * 256) * 8);                  \
    _Pragma("unroll") for (int i_ = 0; i_ < 4; ++i_)                                    \
        gload16(gupb + boff[i_] + kn_, (BB) + (wv * 64 + i_ * 256) * 8);                \
} while (0)

#define G1_COMPUTE(BA, BB) do {                                                         \
    const char* Abc_ = (const char*)(BA);                                               \
    const char* Bbc_ = (const char*)(BB);                                               \
    _Pragma("unroll") for (int kk = 0; kk < 2; ++kk) {                                  \
        const int kc = kk * 4 + (lane >> 4);                                            \
        s16x8 af[4], bg[2], bu[2];                                                      \
        _Pragma("unroll") for (int m = 0; m < 4; ++m) {                                 \
            const int r = wr * 64 + m * 16 + (lane & 15);                               \
            af[m] = *(const s16x8*)(Abc_ + r * 128 + ((kc ^ (r & 7)) << 4)); }          \
        _Pragma("unroll") for (int n = 0; n < 2; ++n) {                                 \
            const int rg = wc * 32 + n * 16 + (lane & 15);                              \
            bg[n] = *(const s16x8*)(Bbc_ + rg * 128 + ((kc ^ (rg & 7)) << 4));          \
            const int ru = rg + 64;                                                     \
            bu[n] = *(const s16x8*)(Bbc_ + ru * 128 + ((kc ^ (ru & 7)) << 4)); }        \
        _Pragma("unroll") for (int m = 0; m < 4; ++m)                                   \
        _Pragma("unroll") for (int n = 0; n < 2; ++n) {                                 \
            ag[m][n] = __builtin_amdgcn_mfma_f32_16x16x32_bf16(af[m], bg[n], ag[m][n], 0, 0, 0); \
            au[m][n] = __builtin_amdgcn_mfma_f32_16x16x32_bf16(af[m], bu[n], au[m][n], 0, 0, 0); } \
    }                                                                                   \
} while (0)

// GEMM1: act = silu(X Wg^T) * (X Wu^T).  tile 128 rows x 64 act-cols (g+u), BK=64, 16 K-steps.
// grid (FF/64=8, MAXBLK); 256 thr = 4 waves (2M x 2N)
__global__ __launch_bounds__(256) void gemm1_bf16(
    const unsigned short* __restrict__ hb,    // [T, D] bf16
    const unsigned short* __restrict__ gupb,  // [E, 2F, D] bf16
    const int* __restrict__ row_slot,
    const int* __restrict__ offsets,
    const int* __restrict__ blk_e,
    const int* __restrict__ blk_by,
    unsigned short* __restrict__ act)         // [NSLOT, F] bf16
{
    const int e = blk_e[blockIdx.y];
    if (e < 0) return;
    const int bx      = blockIdx.x;
    const int lby     = blk_by[blockIdx.y];
    const int rowbase = offsets[e] + lby * BM;
    const int rowlim  = offsets[e + 1] - 1;
    const int nrows   = min(BM, offsets[e + 1] - rowbase);

    __shared__ __align__(16) unsigned short Ab0[BM * 64], Ab1[BM * 64];   // 16 KB each
    __shared__ __align__(16) unsigned short Bb0[128 * 64], Bb1[128 * 64]; // 16 KB each

    const int tid  = threadIdx.x;
    const int lane = tid & 63;
    const int wv   = tid >> 6;
    const int wr   = wv >> 1, wc = wv & 1;

    int aoff[4];
#pragma unroll
    for (int i = 0; i < 4; ++i) {
        const int ch = tid + i * 256;          // 1024 chunks = 128 rows x 8 col-chunks
        const int r = ch >> 3, c = ch & 7;
        int grow = rowbase + r; if (grow > rowlim) grow = rowlim;
        const int tok = row_slot[grow] >> 1;
        aoff[i] = tok * DIM + ((c ^ (r & 7)) << 3);
    }
    int boff[4];
#pragma unroll
    for (int i = 0; i < 4; ++i) {
        const int ch = tid + i * 256;
        const int r = ch >> 3, c = ch & 7;
        const int gr = (r < 64) ? (bx * 64 + r) : (FF + bx * 64 + r - 64);
        boff[i] = e * (2 * FF * DIM) + gr * DIM + ((c ^ (r & 7)) << 3);
    }

    const f32x4 zf = {0.f, 0.f, 0.f, 0.f};
    f32x4 ag[4][2], au[4][2];
#pragma unroll
    for (int m = 0; m < 4; ++m)
#pragma unroll
        for (int n = 0; n < 2; ++n) { ag[m][n] = zf; au[m][n] = zf; }

    G1_STAGE(Ab0, Bb0, 0);
    __syncthreads();

#pragma unroll 1
    for (int t = 0; t < DIM / 64; t += 2) {
        G1_STAGE(Ab1, Bb1, t + 1);
        G1_COMPUTE(Ab0, Bb0);
        __syncthreads();
        if (t + 2 < DIM / 64) G1_STAGE(Ab0, Bb0, t + 2);
        G1_COMPUTE(Ab1, Bb1);
        __syncthreads();
    }

    // epilogue: act = silu(g)*u -> bf16
#pragma unroll
    for (int m = 0; m < 4; ++m)
#pragma unroll
        for (int n = 0; n < 2; ++n) {
            const int col = bx * 64 + wc * 32 + n * 16 + (lane & 15);
#pragma unroll
            for (int i = 0; i < 4; ++i) {
                const int rl = wr * 64 + m * 16 + ((lane >> 4) << 2) + i;
                if (rl < nrows) {
                    const float g = ag[m][n][i];
                    const float u = au[m][n][i];
                    const float a = (g / (1.f + __expf(-g))) * u;
                    act[(size_t)(rowbase + rl) * FF + col] = (unsigned short)f2bf(a);
                }
            }
        }
}

#define G2_STAGE(BA, BB, T) do {                                                        \
    const int kn_ = (T) * 64;                                                           \
    _Pragma("unroll") for (int i_ = 0; i_ < 4; ++i_)                                    \
        gload16(act + aoff[i_] + kn_, (BA) + (wv * 64 + i_ * 256) * 8);                 \
    _Pragma("unroll") for (int i_ = 0; i_ < 4; ++i_)                                    \
        gload16(downb + boff[i_] + kn_, (BB) + (wv * 64 + i_ * 256) * 8);               \
} while (0)

#define G2_COMPUTE(BA, BB) do {                                                         \
    const char* Abc_ = (const char*)(BA);                                               \
    const char* Bbc_ = (const char*)(BB);                                               \
    _Pragma("unroll") for (int kk = 0; kk < 2; ++kk) {                                  \
        const int kc = kk * 4 + (lane >> 4);                                            \
        s16x8 af[4], bf[4];                                                             \
        _Pragma("unroll") for (int m = 0; m < 4; ++m) {                                 \
            const int r = wr * 64 + m * 16 + (lane & 15);                               \
            af[m] = *(const s16x8*)(Abc_ + r * 128 + ((kc ^ (r & 7)) << 4)); }          \
        _Pragma("unroll") for (int n = 0; n < 4; ++n) {                                 \
            const int r = wc * 64 + n * 16 + (lane & 15);                               \
            bf[n] = *(const s16x8*)(Bbc_ + r * 128 + ((kc ^ (r & 7)) << 4)); }          \
        _Pragma("unroll") for (int m = 0; m < 4; ++m)                                   \
        _Pragma("unroll") for (int n = 0; n < 4; ++n)                                   \
            acc[m][n] = __builtin_amdgcn_mfma_f32_16x16x32_bf16(af[m], bf[n], acc[m][n], 0, 0, 0); \
    }                                                                                   \
} while (0)

// GEMM2: per-slot result = act_row @ down^T (UNSCALED), stored dense to outslot.
// MODE 1: f32 outslot; MODE 2: bf16 outslot.  tile 128 x 128, BK=64, 8 K-steps.
// grid (DIM/128=8, MAXBLK); 256 thr = 4 waves (2M x 2N)
template <int MODE>
__global__ __launch_bounds__(256) void gemm2_slot(
    const unsigned short* __restrict__ act,   // [NSLOT, F] bf16
    const unsigned short* __restrict__ downb, // [E, D, F] bf16
    const int* __restrict__ row_slot,
    const int* __restrict__ offsets,
    const int* __restrict__ blk_e,
    const int* __restrict__ blk_by,
    void* __restrict__ outslot)               // [NSLOT, D] f32 or bf16
{
    const int e = blk_e[blockIdx.y];
    if (e < 0) return;
    const int bx      = blockIdx.x;
    const int lby     = blk_by[blockIdx.y];
    const int rowbase = offsets[e] + lby * BM;
    const int nrows   = min(BM, offsets[e + 1] - rowbase);
    const int rowlim  = offsets[e + 1] - 1;

    __shared__ __align__(16) unsigned short Ab0[BM * 64], Ab1[BM * 64];
    __shared__ __align__(16) unsigned short Bb0[128 * 64], Bb1[128 * 64];

    const int tid  = threadIdx.x;
    const int lane = tid & 63;
    const int wv   = tid >> 6;
    const int wr   = wv >> 1, wc = wv & 1;

    int aoff[4];
#pragma unroll
    for (int i = 0; i < 4; ++i) {
        const int ch = tid + i * 256;
        const int r = ch >> 3, c = ch & 7;
        int grow = rowbase + r; if (grow > rowlim) grow = rowlim;
        aoff[i] = grow * FF + ((c ^ (r & 7)) << 3);
    }
    int boff[4];
#pragma unroll
    for (int i = 0; i < 4; ++i) {
        const int ch = tid + i * 256;
        const int r = ch >> 3, c = ch & 7;
        boff[i] = e * (DIM * FF) + (bx * 128 + r) * FF + ((c ^ (r & 7)) << 3);
    }

    const f32x4 zf = {0.f, 0.f, 0.f, 0.f};
    f32x4 acc[4][4];
#pragma unroll
    for (int m = 0; m < 4; ++m)
#pragma unroll
        for (int n = 0; n < 4; ++n) acc[m][n] = zf;

    G2_STAGE(Ab0, Bb0, 0);
    __syncthreads();

#pragma unroll 1
    for (int t = 0; t < FF / 64; t += 2) {
        G2_STAGE(Ab1, Bb1, t + 1);
        G2_COMPUTE(Ab0, Bb0);
        __syncthreads();
        if (t + 2 < FF / 64) G2_STAGE(Ab0, Bb0, t + 2);
        G2_COMPUTE(Ab1, Bb1);
        __syncthreads();
    }

    // epilogue: dense non-conflicting stores to this block's (row, col-range)
#pragma unroll
    for (int m = 0; m < 4; ++m)
#pragma unroll
        for (int i = 0; i < 4; ++i) {
            const int rl = wr * 64 + m * 16 + ((lane >> 4) << 2) + i;
            if (rl < nrows) {
                const size_t base = (size_t)(rowbase + rl) * DIM + bx * 128 + wc * 64 + (lane & 15);
                if (MODE == 1) {
                    float* o = (float*)outslot + base;
#pragma unroll
                    for (int n = 0; n < 4; ++n) o[n * 16] = acc[m][n][i];
                } else {
                    unsigned short* o = (unsigned short*)outslot + base;
#pragma unroll
                    for (int n = 0; n < 4; ++n) o[n * 16] = (unsigned short)f2bf(acc[m][n][i]);
                }
            }
        }
}

// combine: out[t] = w0 * outslot[pos(2t)] + w1 * outslot[pos(2t+1)]
template <int MODE>
__global__ __launch_bounds__(256) void combine_k(
    const void* __restrict__ outslot,
    const int* __restrict__ slot_pos,
    const float* __restrict__ tkw,
    float* __restrict__ out)
{
    const int i = blockIdx.x * 256 + threadIdx.x;   // [0, T*D/8)
    const int t = i >> 7;                            // DIM/8 = 128 chunks/token
    const int d = (i & 127) << 3;
    const int p0 = slot_pos[2 * t], p1 = slot_pos[2 * t + 1];
    const float w0 = tkw[2 * t],    w1 = tkw[2 * t + 1];
    float r0[8], r1[8];
    if (MODE == 1) {
        const float* s0 = (const float*)outslot + (size_t)p0 * DIM + d;
        const float* s1 = (const float*)outslot + (size_t)p1 * DIM + d;
        float4 a0 = *(const float4*)s0, a1 = *(const float4*)(s0 + 4);
        float4 b0 = *(const float4*)s1, b1 = *(const float4*)(s1 + 4);
        r0[0]=a0.x; r0[1]=a0.y; r0[2]=a0.z; r0[3]=a0.w; r0[4]=a1.x; r0[5]=a1.y; r0[6]=a1.z; r0[7]=a1.w;
        r1[0]=b0.x; r1[1]=b0.y; r1[2]=b0.z; r1[3]=b0.w; r1[4]=b1.x; r1[5]=b1.y; r1[6]=b1.z; r1[7]=b1.w;
    } else {
        const s16x8 a = *(const s16x8*)((const unsigned short*)outslot + (size_t)p0 * DIM + d);
        const s16x8 b = *(const s16x8*)((const unsigned short*)outslot + (size_t)p1 * DIM + d);
#pragma unroll
        for (int j = 0; j < 8; ++j) { r0[j] = bf2f((unsigned short)a[j]); r1[j] = bf2f((unsigned short)b[j]); }
    }
    float4 o0, o1;
    o0.x = w0*r0[0]+w1*r1[0]; o0.y = w0*r0[1]+w1*r1[1]; o0.z = w0*r0[2]+w1*r1[2]; o0.w = w0*r0[3]+w1*r1[3];
    o1.x = w0*r0[4]+w1*r1[4]; o1.y = w0*r0[5]+w1*r1[5]; o1.z = w0*r0[6]+w1*r1[6]; o1.w = w0*r0[7]+w1*r1[7];
    float* op = out + (size_t)t * DIM + d;
    *(float4*)op = o0;
    *(float4*)(op + 4) = o1;
}

// ================= fallback path (f32 in-kernel convert, atomic out) =================

__global__ __launch_bounds__(256) void moe_gemm1(
    const float* __restrict__ hidden, const float* __restrict__ gup,
    const int* __restrict__ row_slot, const int* __restrict__ offsets,
    unsigned short* __restrict__ act)
{
    const int e = blockIdx.z;
    const int row0 = offsets[e];
    const int n_e = offsets[e + 1] - row0;
    const int by = blockIdx.y;
    if (by * 128 >= n_e) return;
    const int bx = blockIdx.x;
    __shared__ __align__(16) unsigned short Abuf[128 * 64];
    __shared__ __align__(16) unsigned short Bbuf[128 * 64];
    char* Ab = (char*)Abuf; char* Bb = (char*)Bbuf;
    const int tid = threadIdx.x, lane = tid & 63, wv = tid >> 6;
    const int wr = wv >> 1, wc = wv & 1;
    const float* aptr[4]; const float* bptr[4]; int soff[4];
#pragma unroll
    for (int i = 0; i < 4; ++i) {
        const int chunk = tid + i * 256;
        const int r = chunk >> 3, c = chunk & 7;
        soff[i] = r * 128 + ((c ^ (r & 7)) << 4);
        int rr = by * 128 + r; if (rr >= n_e) rr = n_e - 1;
        const int slot = row_slot[row0 + rr];
        aptr[i] = hidden + (size_t)(slot >> 1) * DIM + c * 8;
        const int gr = (r < 64) ? (bx * 64 + r) : (FF + bx * 64 + (r - 64));
        bptr[i] = gup + (size_t)e * (2 * FF * DIM) + (size_t)gr * DIM + c * 8;
    }
    const f32x4 zf = {0.f, 0.f, 0.f, 0.f};
    f32x4 acc_g[4][2], acc_u[4][2];
#pragma unroll
    for (int m = 0; m < 4; ++m)
#pragma unroll
        for (int n = 0; n < 2; ++n) { acc_g[m][n] = zf; acc_u[m][n] = zf; }
    for (int k0 = 0; k0 < DIM; k0 += 64) {
        __syncthreads();
#pragma unroll
        for (int i = 0; i < 4; ++i) *(int4*)(Ab + soff[i]) = cvt8(aptr[i] + k0);
#pragma unroll
        for (int i = 0; i < 4; ++i) *(int4*)(Bb + soff[i]) = cvt8(bptr[i] + k0);
        __syncthreads();
#pragma unroll
        for (int kk = 0; kk < 2; ++kk) {
            const int kc = kk * 4 + (lane >> 4);
            s16x8 af[4], bg[2], bu[2];
#pragma unroll
            for (int m = 0; m < 4; ++m) {
                const int r = wr * 64 + m * 16 + (lane & 15);
                af[m] = *(const s16x8*)(Ab + r * 128 + ((kc ^ (r & 7)) << 4));
            }
#pragma unroll
            for (int n = 0; n < 2; ++n) {
                const int rg = wc * 32 + n * 16 + (lane & 15);
                bg[n] = *(const s16x8*)(Bb + rg * 128 + ((kc ^ (rg & 7)) << 4));
                const int ru = rg + 64;
                bu[n] = *(const s16x8*)(Bb + ru * 128 + ((kc ^ (ru & 7)) << 4));
            }
#pragma unroll
            for (int m = 0; m < 4; ++m)
#pragma unroll
                for (int n = 0; n < 2; ++n) {
                    acc_g[m][n] = __builtin_amdgcn_mfma_f32_16x16x32_bf16(af[m], bg[n], acc_g[m][n], 0, 0, 0);
                    acc_u[m][n] = __builtin_amdgcn_mfma_f32_16x16x32_bf16(af[m], bu[n], acc_u[m][n], 0, 0, 0);
                }
        }
    }
#pragma unroll
    for (int m = 0; m < 4; ++m)
#pragma unroll
        for (int n = 0; n < 2; ++n) {
            const int col = bx * 64 + wc * 32 + n * 16 + (lane & 15);
#pragma unroll
            for (int i = 0; i < 4; ++i) {
                const int rl = wr * 64 + m * 16 + ((lane >> 4) << 2) + i;
                const int rr = by * 128 + rl;
                if (rr < n_e) {
                    const float g = acc_g[m][n][i];
                    const float u = acc_u[m][n][i];
                    const float a = (g / (1.f + __expf(-g))) * u;
                    act[(size_t)(row0 + rr) * FF + col] = (unsigned short)f2bf(a);
                }
            }
        }
}

__global__ __launch_bounds__(256) void moe_gemm2(
    const unsigned short* __restrict__ act, const float* __restrict__ down,
    const int* __restrict__ row_slot, const int* __restrict__ offsets,
    const float* __restrict__ tkw, float* __restrict__ out)
{
    const int e = blockIdx.z;
    const int row0 = offsets[e];
    const int n_e = offsets[e + 1] - row0;
    const int by = blockIdx.y;
    if (by * 128 >= n_e) return;
    const int bx = blockIdx.x;
    __shared__ __align__(16) unsigned short Abuf[128 * 64];
    __shared__ __align__(16) unsigned short Bbuf[128 * 64];
    char* Ab = (char*)Abuf; char* Bb = (char*)Bbuf;
    const int tid = threadIdx.x, lane = tid & 63, wv = tid >> 6;
    const int wr = wv >> 1, wc = wv & 1;
    const unsigned short* aptr[4]; const float* bptr[4]; int soff[4];
#pragma unroll
    for (int i = 0; i < 4; ++i) {
        const int chunk = tid + i * 256;
        const int r = chunk >> 3, c = chunk & 7;
        soff[i] = r * 128 + ((c ^ (r & 7)) << 4);
        int rr = by * 128 + r; if (rr >= n_e) rr = n_e - 1;
        aptr[i] = act + (size_t)(row0 + rr) * FF + c * 8;
        bptr[i] = down + (size_t)e * (DIM * FF) + (size_t)(bx * 128 + r) * FF + c * 8;
    }
    const f32x4 zf = {0.f, 0.f, 0.f, 0.f};
    f32x4 acc[4][4];
#pragma unroll
    for (int m = 0; m < 4; ++m)
#pragma unroll
        for (int n = 0; n < 4; ++n) acc[m][n] = zf;
    for (int k0 = 0; k0 < FF; k0 += 64) {
        __syncthreads();
#pragma unroll
        for (int i = 0; i < 4; ++i) *(int4*)(Ab + soff[i]) = *(const int4*)(aptr[i] + k0);
#pragma unroll
        for (int i = 0; i < 4; ++i) *(int4*)(Bb + soff[i]) = cvt8(bptr[i] + k0);
        __syncthreads();
#pragma unroll
        for (int kk = 0; kk < 2; ++kk) {
            const int kc = kk * 4 + (lane >> 4);
            s16x8 af[4], bf[4];
#pragma unroll
            for (int m = 0; m < 4; ++m) {
                const int r = wr * 64 + m * 16 + (lane & 15);
                af[m] = *(const s16x8*)(Ab + r * 128 + ((kc ^ (r & 7)) << 4));
            }
#pragma unroll
            for (int n = 0; n < 4; ++n) {
                const int r = wc * 64 + n * 16 + (lane & 15);
                bf[n] = *(const s16x8*)(Bb + r * 128 + ((kc ^ (r & 7)) << 4));
            }
#pragma unroll
            for (int m = 0; m < 4; ++m)
#pragma unroll
                for (int n = 0; n < 4; ++n)
                    acc[m][n] = __builtin_amdgcn_mfma_f32_16x16x32_bf16(af[m], bf[n], acc[m][n], 0, 0, 0);
        }
    }
#pragma unroll
    for (int m = 0; m < 4; ++m)
#pragma unroll
        for (int i = 0; i < 4; ++i) {
            const int rl = wr * 64 + m * 16 + ((lane >> 4) << 2) + i;
            const int rr = by * 128 + rl;
            if (rr < n_e) {
                const int slot = row_slot[row0 + rr];
                const float w = tkw[slot];
                float* orow = out + (size_t)(slot >> 1) * DIM + bx * 128 + wc * 64 + (lane & 15);
#pragma unroll
                for (int n = 0; n < 4; ++n)
                    unsafeAtomicAdd(orow + n * 16, acc[m][n][i] * w);
            }
        }
}

extern "C" void kernel_launch(void* const* d_in, const int* in_sizes, int n_in,
                              void* d_out, int out_size, void* d_ws, size_t ws_size,
                              hipStream_t stream)
{
    const float* hidden = (const float*)d_in[0];
    const int*   idx    = (const int*)  d_in[1];
    const float* tkw    = (const float*)d_in[2];
    const float* gup    = (const float*)d_in[3];
    const float* down   = (const float*)d_in[4];
    float* out = (float*)d_out;

    // workspace layout
    const size_t ACT = (size_t)NSLOT * FF * 2;        // 16 MB
    const size_t HB  = (size_t)T_TOK * DIM * 2;       // 16 MB
    const size_t GB  = (size_t)NE * 2 * FF * DIM * 2; // 16 MB
    const size_t DB  = (size_t)NE * DIM * FF * 2;     //  8 MB
    const size_t RS  = (size_t)NSLOT * 4;             // 64 KB (row_slot)
    const size_t SP  = (size_t)NSLOT * 4;             // 64 KB (slot_pos)
    const size_t CTRL = 8192;                         // offsets + blk tables + partials
    const size_t OS32 = (size_t)NSLOT * DIM * 4;      // 64 MB (f32 outslot)
    const size_t OS16 = (size_t)NSLOT * DIM * 2;      // 32 MB (bf16 outslot)
    char* ws = (char*)d_ws;
    unsigned short* act = (unsigned short*)ws;

    const size_t base_need = ACT + HB + GB + DB + RS + SP + CTRL;
    int mode;                       // 1: f32 slot, 2: bf16 slot, 0: legacy atomic
    if      (ws_size >= base_need + OS32) mode = 1;
    else if (ws_size >= base_need + OS16) mode = 2;
    else if (ws_size >= ACT + RS + SP + CTRL) mode = 0;
    else mode = -1;
    if (mode < 0) return;

    unsigned short *hb = nullptr, *gb = nullptr, *db = nullptr;
    int *row_slot, *ctrl; void* outslot = nullptr;
    if (mode == 1 || mode == 2) {
        hb = (unsigned short*)(ws + ACT);
        gb = (unsigned short*)(ws + ACT + HB);
        db = (unsigned short*)(ws + ACT + HB + GB);
        row_slot = (int*)(ws + ACT + HB + GB + DB);
        ctrl     = (int*)(ws + ACT + HB + GB + DB + RS + SP);
        outslot  = (void*)(ws + base_need);
    } else {
        row_slot = (int*)(ws + ACT);
        ctrl     = (int*)(ws + ACT + RS + SP);
    }
    int* slot_pos = row_slot + NSLOT;
    int* offsets = ctrl;                         // [NE+1] (16 slots reserved)
    int* blk_e   = ctrl + 16;                    // [MAXBLK]
    int* blk_by  = ctrl + 16 + MAXBLK;           // [MAXBLK]
    int* cursor  = ctrl + 16 + 2 * MAXBLK;       // [8]
    int* partial = cursor + 8;                   // [64*8]

    if (mode == 0)
        hipMemsetAsync(out, 0, (size_t)T_TOK * DIM * sizeof(float), stream);

    route_count  <<<NSLOT / 256, 256, 0, stream>>>(idx, partial);
    route_scan   <<<1, 64, 0, stream>>>(partial, offsets, cursor, blk_e, blk_by);
    route_scatter<<<NSLOT / 256, 256, 0, stream>>>(idx, cursor, row_slot, slot_pos);

    if (mode == 1 || mode == 2) {
        cvt_all<<<2048, 256, 0, stream>>>(hidden, gup, down, hb, gb, db);
        gemm1_bf16<<<dim3(FF / 64, MAXBLK), 256, 0, stream>>>(
            hb, gb, row_slot, offsets, blk_e, blk_by, act);
        if (mode == 1) {
            gemm2_slot<1><<<dim3(DIM / 128, MAXBLK), 256, 0, stream>>>(
                act, db, row_slot, offsets, blk_e, blk_by, outslot);
            combine_k<1><<<T_TOK * DIM / 8 / 256, 256, 0, stream>>>(outslot, slot_pos, tkw, out);
        } else {
            gemm2_slot<2><<<dim3(DIM / 128, MAXBLK), 256, 0, stream>>>(
                act, db, row_slot, offsets, blk_e, blk_by, outslot);
            combine_k<2><<<T_TOK * DIM / 8 / 256, 256, 0, stream>>>(outslot, slot_pos, tkw, out);
        }
    } else {
        moe_gemm1<<<dim3(FF / 64, 128, NE), 256, 0, stream>>>(hidden, gup, row_slot, offsets, act);
        moe_gemm2<<<dim3(DIM / 128, 128, NE), 256, 0, stream>>>(act, down, row_slot, offsets, tkw, out);
    }
}